// Round 4
// baseline (6428.761 us; speedup 1.0000x reference)
//
#include <hip/hip_runtime.h>

#define T_STEPS 512
#define BATCH   32
#define DIM     256
#define UNITS   256
#define COLS4U  1024
#define NCAND   64

typedef _Float16 half8  __attribute__((ext_vector_type(8)));
typedef _Float16 half4v __attribute__((ext_vector_type(4)));
typedef float    f32x4  __attribute__((ext_vector_type(4)));
typedef unsigned long long ull;
typedef ull      ull2   __attribute__((ext_vector_type(2)));

__device__ __forceinline__ float fsig(float x){ return 1.0f/(1.0f+__expf(-x)); }
__device__ __forceinline__ float ftanh(float x){
  float xx=fminf(fmaxf(x,-15.f),15.f);
  float e=__expf(2.f*xx);
  return (e-1.f)/(e+1.f);
}
// byte offset into a [32][256] f16 LDS plane, XOR-swizzled 16B granules
__device__ __forceinline__ int swz(int b,int u){
  int g=u>>3; int s=(g&7)^(b&7);
  return b*512 + (g>>3)*128 + s*16 + (u&7)*2;
}

// ============================================================================
// Phase 1 (unchanged from r3, proven): xp[dir][t][col][b] fp16 = b + x@Wk
// ============================================================================
__global__ __launch_bounds__(256, 2) void xproj(
    const float* __restrict__ x,
    const float* __restrict__ Wk_f, const float* __restrict__ b_f,
    const float* __restrict__ Wk_b, const float* __restrict__ b_b,
    _Float16* __restrict__ xph)
{
  const int bx  = blockIdx.x;
  const int dir = bx >> 8;
  const int cg  = (bx >> 5) & 7;
  const int tg  = bx & 31;
  const int tid = threadIdx.x;
  const int w   = tid >> 6;
  const int lane= tid & 63;
  const int l15 = lane & 15;
  const int l4  = lane >> 4;

  const float* Wk = dir ? Wk_b : Wk_f;
  const float* bs = dir ? b_b  : b_f;

  const int col0 = cg*128 + w*32;

  half8 Bf[2][8];
  float bias[2];
#pragma unroll
  for (int nt=0; nt<2; nt++){
    const int col = col0 + nt*16 + l15;
    bias[nt] = bs[col];
#pragma unroll
    for (int kk=0; kk<8; kk++){
      half8 v;
#pragma unroll
      for (int r=0; r<8; r++) v[r] = (_Float16)Wk[(size_t)(kk*32 + l4*8 + r)*COLS4U + col];
      Bf[nt][kk] = v;
    }
  }

  for (int tt=0; tt<16; ++tt){
    const int t   = tg*16 + tt;
    const int tin = dir ? (T_STEPS-1-t) : t;

    half8 Af[2][8];
#pragma unroll
    for (int mt=0; mt<2; mt++){
      const int b = mt*16 + l15;
#pragma unroll
      for (int kk=0; kk<8; kk++){
        const float* xp_ = x + ((size_t)b*T_STEPS + tin)*DIM + kk*32 + l4*8;
        f32x4 u0 = *(const f32x4*)xp_;
        f32x4 u1 = *(const f32x4*)(xp_ + 4);
        half8 v;
        v[0]=(_Float16)u0[0]; v[1]=(_Float16)u0[1]; v[2]=(_Float16)u0[2]; v[3]=(_Float16)u0[3];
        v[4]=(_Float16)u1[0]; v[5]=(_Float16)u1[1]; v[6]=(_Float16)u1[2]; v[7]=(_Float16)u1[3];
        Af[mt][kk] = v;
      }
    }

    f32x4 acc[2][2];
#pragma unroll
    for (int nt=0; nt<2; nt++){
      f32x4 a; a[0]=bias[nt]; a[1]=bias[nt]; a[2]=bias[nt]; a[3]=bias[nt];
      acc[nt][0]=a; acc[nt][1]=a;
    }
#pragma unroll
    for (int kk=0; kk<8; kk++)
#pragma unroll
      for (int nt=0; nt<2; nt++)
#pragma unroll
        for (int mt=0; mt<2; mt++)
          acc[nt][mt] = __builtin_amdgcn_mfma_f32_16x16x32_f16(Af[mt][kk], Bf[nt][kk], acc[nt][mt], 0,0,0);

#pragma unroll
    for (int nt=0; nt<2; nt++){
      const int col = col0 + nt*16 + l15;
#pragma unroll
      for (int mt=0; mt<2; mt++){
        half4v o;
        o[0]=(_Float16)acc[nt][mt][0]; o[1]=(_Float16)acc[nt][mt][1];
        o[2]=(_Float16)acc[nt][mt][2]; o[3]=(_Float16)acc[nt][mt][3];
        *(ull*)(xph + ((size_t)(dir*T_STEPS + t)*COLS4U + col)*BATCH + mt*16 + l4*4)
            = __builtin_bit_cast(ull, o);
      }
    }
  }
}

// ============================================================================
// Phase 2: elected same-XCD scan. MODE 0 = volatile L2 ld/st (same-XCD pair),
// MODE 1 = agent-scope atomics (fallback, any placement).
// ============================================================================
template<int MODE>
__device__ __forceinline__ void scan_body(
    int dir, int g4, const float* __restrict__ Wr, float* __restrict__ out,
    const _Float16* __restrict__ xph, unsigned* __restrict__ slices,
    _Float16 (*hlds)[BATCH*UNITS])
{
  const int tid=threadIdx.x;
  const int w=tid>>6, lane=tid&63, l15=lane&15, l4=lane>>4;
  const int uloc=w*16+l15, unit=g4*64+uloc, outcol=dir*256+unit;

  half8 Bf[4][8];
#pragma unroll
  for(int q=0;q<4;q++){
    const int col=q*256+unit;
#pragma unroll
    for(int kk=0;kk<8;kk++){
      half8 v;
#pragma unroll
      for(int r=0;r<8;r++) v[r]=(_Float16)Wr[(size_t)(kk*32+l4*8+r)*COLS4U+col];
      Bf[q][kk]=v;
      __builtin_amdgcn_sched_barrier(0);
    }
  }

  {
    half8 z;
#pragma unroll
    for(int e=0;e<8;e++) z[e]=(_Float16)0.f;
    for(int i=tid;i<BATCH*UNITS/8;i+=256) ((half8*)hlds[0])[i]=z;
  }
  __syncthreads();

  float cst[8];
#pragma unroll
  for(int i=0;i<8;i++) cst[i]=0.f;
  bool spin_ok=true;

  ull xpv[8];
#pragma unroll
  for(int q=0;q<4;q++)
#pragma unroll
    for(int mt=0;mt<2;mt++)
      xpv[q*2+mt]=*(const ull*)(xph+((size_t)(dir*T_STEPS+0)*COLS4U+q*256+unit)*BATCH+mt*16+l4*4);

  const int b_r=lane>>1, u0r=(lane&1)*32;
  const int pw=(w<3)?(w+(w>=g4)):0;   // peer g4 id for reader waves 0..2

  for(int t=0;t<T_STEPS;++t){
    // ---- acc init from xp ----
    f32x4 acc[2][4];
#pragma unroll
    for(int q=0;q<4;q++)
#pragma unroll
      for(int mt=0;mt<2;mt++){
        half4v hv=__builtin_bit_cast(half4v,xpv[q*2+mt]);
        f32x4 a; a[0]=(float)hv[0];a[1]=(float)hv[1];a[2]=(float)hv[2];a[3]=(float)hv[3];
        acc[mt][q]=a;
      }

    // ---- z += h_t @ Wr ----
    const char* hpl=(const char*)hlds[t&1];
#pragma unroll
    for(int kk=0;kk<8;kk++){
      const int ul=kk*32+l4*8;
      half8 a0=*(const half8*)(hpl+swz(l15,ul));
      half8 a1=*(const half8*)(hpl+swz(16+l15,ul));
#pragma unroll
      for(int q=0;q<4;q++){
        acc[0][q]=__builtin_amdgcn_mfma_f32_16x16x32_f16(a0,Bf[q][kk],acc[0][q],0,0,0);
        acc[1][q]=__builtin_amdgcn_mfma_f32_16x16x32_f16(a1,Bf[q][kk],acc[1][q],0,0,0);
      }
    }

    // ---- gates -> c,h ; LDS write + tagged publish + out ----
    const int tout=dir?(T_STEPS-1-t):t;
    const int par=(t+1)&1;
    unsigned* myslc=slices+((size_t)(par*8+dir*4+g4))*2048;
    const unsigned tgt=(unsigned)(t+1)&0xFFFFu;
    char* hnx=(char*)hlds[(t+1)&1];
#pragma unroll
    for(int mt=0;mt<2;mt++){
#pragma unroll
      for(int r=0;r<4;r++){
        const int b=mt*16+l4*4+r;
        float iv=fsig(acc[mt][0][r]);
        float fv=fsig(acc[mt][1][r]);
        float gv=ftanh(acc[mt][2][r]);
        float ov=fsig(acc[mt][3][r]);
        float &c=cst[mt*4+r];
        c=fv*c+iv*gv;
        float hv=ov*ftanh(c);
        _Float16 hf=(_Float16)hv;
        if(t+1<T_STEPS){
          unsigned word=((unsigned)__builtin_bit_cast(unsigned short,hf)<<16)|tgt;
          if(MODE==0) *(volatile unsigned*)&myslc[b*64+uloc]=word;
          else __hip_atomic_store(&myslc[b*64+uloc],word,__ATOMIC_RELAXED,__HIP_MEMORY_SCOPE_AGENT);
        }
        *(_Float16*)(hnx+swz(b,unit))=hf;
        out[((size_t)b*T_STEPS+tout)*(2*UNITS)+outcol]=hv;
        if(t==T_STEPS-1)
          out[(size_t)BATCH*T_STEPS*(2*UNITS)+(size_t)b*(2*UNITS)+outcol]=hv;
      }
    }

    // ---- prefetch xp(t+1), spin-read peer slice (tag==t+1), stage to LDS ----
    if(t+1<T_STEPS){
#pragma unroll
      for(int q=0;q<4;q++)
#pragma unroll
        for(int mt=0;mt<2;mt++)
          xpv[q*2+mt]=*(const ull*)(xph+((size_t)(dir*T_STEPS+(t+1))*COLS4U+q*256+unit)*BATCH+mt*16+l4*4);

      if(w<3){
        const unsigned* src=slices+((size_t)(par*8+dir*4+pw))*2048 + b_r*64 + u0r;
        unsigned wbuf[32];
        if(spin_ok){
          int sp=0; bool ok;
          do{
            ok=true;
#pragma unroll
            for(int k=0;k<32;k++){
              unsigned v=(MODE==0)? *(volatile const unsigned*)(src+k)
                 : __hip_atomic_load(src+k,__ATOMIC_RELAXED,__HIP_MEMORY_SCOPE_AGENT);
              wbuf[k]=v; ok &= ((v&0xFFFFu)==tgt);
            }
            if(++sp>(1<<17)){spin_ok=false;break;}
          }while(!ok);
        } else {
#pragma unroll
          for(int k=0;k<32;k++)
            wbuf[k]=(MODE==0)? *(volatile const unsigned*)(src+k)
               : __hip_atomic_load(src+k,__ATOMIC_RELAXED,__HIP_MEMORY_SCOPE_AGENT);
        }
#pragma unroll
        for(int j=0;j<4;j++){
          half8 hh;
#pragma unroll
          for(int e=0;e<8;e++)
            hh[e]=__builtin_bit_cast(_Float16,(unsigned short)(wbuf[j*8+e]>>16));
          *(half8*)(hnx+swz(b_r,pw*64+u0r+j*8))=hh;
        }
      }
    }
    __syncthreads();
  }
}

__global__ __launch_bounds__(256,1) void bilstm_scan_xcd(
    const float* __restrict__ Wr_f, const float* __restrict__ Wr_b,
    float* __restrict__ out, const _Float16* __restrict__ xph,
    unsigned* __restrict__ slices, unsigned* __restrict__ regtab)
{
  __shared__ _Float16 hlds[2][BATCH*UNITS];
  __shared__ unsigned stab[NCAND];
  __shared__ int sinfo[2];
  const int tid=threadIdx.x;

  // ---- register (bid -> xcd), then wave 0 snapshots the full table ----
  if(tid==0){
    unsigned xv;
    asm volatile("s_getreg_b32 %0, hwreg(HW_REG_XCC_ID)":"=s"(xv));
    __hip_atomic_store(&regtab[blockIdx.x],0x100u|(xv&0xFu),
                       __ATOMIC_RELAXED,__HIP_MEMORY_SCOPE_AGENT);
  }
  if(tid<NCAND){
    unsigned v; int sp=0;
    for(;;){
      v=__hip_atomic_load(&regtab[tid],__ATOMIC_RELAXED,__HIP_MEMORY_SCOPE_AGENT);
      if(__all((v&0x100u)!=0)) break;
      if(++sp>(1<<17)) break;
    }
    stab[tid]=v;
  }
  __syncthreads();

  // ---- deterministic election from identical table snapshot ----
  if(tid==0){
    bool full=true;
    for(int i=0;i<NCAND;i++) if(!(stab[i]&0x100u)){full=false;break;}
    int role=-1, mode=0;
    if(full){
      int cnt[8]={0,0,0,0,0,0,0,0};
      for(int i=0;i<NCAND;i++) cnt[stab[i]&7]++;
      int x0=-1,x1=-1;
      for(int a=0;a<8;a++) if(cnt[a]>=4){x0=a;break;}
      for(int a=0;a<8;a++) if(a!=x0&&cnt[a]>=4){x1=a;break;}
      if(x1<0) x1=x0;                     // then cnt[x0]>=8 by pigeonhole
      const int myb=(int)blockIdx.x;
      const int myx=stab[myb]&7;
      int rank=0;
      for(int i=0;i<myb;i++) if((stab[i]&7)==myx) rank++;
      if(x1==x0){ if(myx==x0&&rank<8) role=rank; }
      else{ if(myx==x0&&rank<4) role=rank; else if(myx==x1&&rank<4) role=4+rank; }
    } else { mode=1; if(blockIdx.x<8) role=(int)blockIdx.x; }
    sinfo[0]=role; sinfo[1]=mode;
  }
  __syncthreads();
  const int role=sinfo[0];
  if(role<0) return;
  const int dir=role>>2, g4=role&3;
  const float* Wr=dir?Wr_b:Wr_f;
  if(sinfo[1]==0) scan_body<0>(dir,g4,Wr,out,xph,slices,hlds);
  else            scan_body<1>(dir,g4,Wr,out,xph,slices,hlds);
}

// ============================================================================
// Fallback for small ws (round-2 proven fused kernel)
// ============================================================================
__global__ __launch_bounds__(256,1) void bilstm_mfma(
    const float* __restrict__ x,
    const float* __restrict__ Wk_f, const float* __restrict__ Wr_f, const float* __restrict__ b_f,
    const float* __restrict__ Wk_b, const float* __restrict__ Wr_b, const float* __restrict__ b_b,
    float* __restrict__ out,
    unsigned short* __restrict__ slices,
    unsigned* __restrict__ flags)
{
  const int dir = blockIdx.x >> 2;
  const int g4  = blockIdx.x & 3;
  const int tid = threadIdx.x;
  const int w   = tid >> 6;
  const int lane= tid & 63;
  const int l15 = lane & 15;
  const int l4  = lane >> 4;

  const float* Wk = dir ? Wk_b : Wk_f;
  const float* Wr = dir ? Wr_b : Wr_f;
  const float* bs = dir ? b_b  : b_f;

  const int u0b   = g4*64;
  const int upl   = u0b + w*16 + l15;
  const int outcol= dir*256 + upl;

  __shared__ _Float16 xlds[BATCH*DIM];
  __shared__ _Float16 hlds[2][BATCH*UNITS];

  half8 Bf[4][16];
#pragma unroll
  for (int q=0;q<4;q++){
    const int col = q*256 + upl;
#pragma unroll
    for (int kk=0;kk<16;kk++){
      const float* Ws = (kk<8) ? Wk : Wr;
      const int k0 = (kk&7)*32 + l4*8;
      half8 v;
#pragma unroll
      for (int r=0;r<8;r++) v[r] = (_Float16)Ws[(size_t)(k0+r)*COLS4U + col];
      Bf[q][kk] = v;
      __builtin_amdgcn_sched_barrier(0);
    }
  }

  float bias[4];
#pragma unroll
  for (int q=0;q<4;q++) bias[q] = bs[q*256 + upl];

  {
    half8 z;
#pragma unroll
    for (int e=0;e<8;e++) z[e] = (_Float16)0.f;
    for (int i=tid; i<BATCH*UNITS/8; i+=256) ((half8*)hlds[0])[i] = z;
  }

  const int bx  = tid >> 3;
  const int d0x = (tid & 7) * 32;
  float xr[32];
  {
    const int tin0 = dir ? (T_STEPS-1) : 0;
    const float* xp = x + ((size_t)bx*T_STEPS + tin0)*DIM + d0x;
#pragma unroll
    for (int i=0;i<8;i++){
      f32x4 v = *(const f32x4*)(xp + i*4);
      xr[i*4+0]=v[0]; xr[i*4+1]=v[1]; xr[i*4+2]=v[2]; xr[i*4+3]=v[3];
    }
#pragma unroll
    for (int j=0;j<4;j++){
      half8 hh;
#pragma unroll
      for (int e=0;e<8;e++) hh[e] = (_Float16)xr[j*8+e];
      *(half8*)((char*)xlds + swz(bx, d0x + j*8)) = hh;
    }
  }
  __syncthreads();

  float cst[8];
#pragma unroll
  for (int i=0;i<8;i++) cst[i]=0.f;
  bool spin_ok = true;

  for (int t=0; t<T_STEPS; ++t){
    if (t+1 < T_STEPS){
      const int tin = dir ? (T_STEPS-2-t) : (t+1);
      const float* xp = x + ((size_t)bx*T_STEPS + tin)*DIM + d0x;
#pragma unroll
      for (int i=0;i<8;i++){
        f32x4 v = *(const f32x4*)(xp + i*4);
        xr[i*4+0]=v[0]; xr[i*4+1]=v[1]; xr[i*4+2]=v[2]; xr[i*4+3]=v[3];
      }
    }

    f32x4 acc[2][4];
#pragma unroll
    for (int q=0;q<4;q++){
      f32x4 a; a[0]=bias[q]; a[1]=bias[q]; a[2]=bias[q]; a[3]=bias[q];
      acc[0][q]=a; acc[1][q]=a;
    }
    const char* hpl = (const char*)hlds[t&1];
#pragma unroll
    for (int kk=0;kk<16;kk++){
      const char* pl = (kk<8) ? (const char*)xlds : hpl;
      const int ul = (kk&7)*32 + l4*8;
      half8 a0 = *(const half8*)(pl + swz(l15,      ul));
      half8 a1 = *(const half8*)(pl + swz(16+l15,   ul));
#pragma unroll
      for (int q=0;q<4;q++){
        acc[0][q] = __builtin_amdgcn_mfma_f32_16x16x32_f16(a0, Bf[q][kk], acc[0][q], 0,0,0);
        acc[1][q] = __builtin_amdgcn_mfma_f32_16x16x32_f16(a1, Bf[q][kk], acc[1][q], 0,0,0);
      }
    }

    const int tout = dir ? (T_STEPS-1-t) : t;
    unsigned short* slc = slices + (((size_t)((t+1)&1))*8 + dir*4 + g4)*2048;
    char* hnx = (char*)hlds[(t+1)&1];
#pragma unroll
    for (int mt=0; mt<2; mt++){
#pragma unroll
      for (int r=0;r<4;r++){
        const int b = mt*16 + l4*4 + r;
        float iv = fsig (acc[mt][0][r]);
        float fv = fsig (acc[mt][1][r]);
        float gv = ftanh(acc[mt][2][r]);
        float ov = fsig (acc[mt][3][r]);
        float &c = cst[mt*4+r];
        c = fv*c + iv*gv;
        float hval = ov*ftanh(c);
        out[((size_t)b*T_STEPS + tout)*(2*UNITS) + outcol] = hval;
        if (t == T_STEPS-1)
          out[(size_t)BATCH*T_STEPS*(2*UNITS) + (size_t)b*(2*UNITS) + outcol] = hval;
        _Float16 hf = (_Float16)hval;
        *(_Float16*)(hnx + swz(b, upl)) = hf;
        if (t+1 < T_STEPS)
          __hip_atomic_store(&slc[b*64 + (w*16+l15)],
                             __builtin_bit_cast(unsigned short, hf),
                             __ATOMIC_RELAXED, __HIP_MEMORY_SCOPE_AGENT);
      }
    }
    __syncthreads();

    if (t+1 < T_STEPS){
      if (tid == 192)
        __hip_atomic_store(&flags[(dir*4+g4)*32], (unsigned)(t+1),
                           __ATOMIC_RELAXED, __HIP_MEMORY_SCOPE_AGENT);
#pragma unroll
      for (int j=0;j<4;j++){
        half8 hh;
#pragma unroll
        for (int e=0;e<8;e++) hh[e] = (_Float16)xr[j*8+e];
        *(half8*)((char*)xlds + swz(bx, d0x + j*8)) = hh;
      }
      if (w < 3){
        const int p = w + (w >= g4);
        const unsigned target = (unsigned)(t+1);
        if (spin_ok){
          int sp = 0;
          while (__hip_atomic_load(&flags[(dir*4+p)*32],
                                   __ATOMIC_RELAXED, __HIP_MEMORY_SCOPE_AGENT) < target){
            if (++sp > (1<<22)) { spin_ok = false; break; }
          }
        }
        const ull* src = (const ull*)(slices + (((size_t)((t+1)&1))*8 + dir*4 + p)*2048);
        const int bsl = lane >> 1;
        const int u00 = (lane & 1) * 32;
#pragma unroll
        for (int j=0;j<4;j++){
          ull v0 = __hip_atomic_load(&src[lane*8 + 2*j  ], __ATOMIC_RELAXED, __HIP_MEMORY_SCOPE_AGENT);
          ull v1 = __hip_atomic_load(&src[lane*8 + 2*j+1], __ATOMIC_RELAXED, __HIP_MEMORY_SCOPE_AGENT);
          ull2 vv; vv[0]=v0; vv[1]=v1;
          *(ull2*)(hnx + swz(bsl, p*64 + u00 + j*8)) = vv;
        }
      }
      __syncthreads();
    }
  }
}

extern "C" void kernel_launch(void* const* d_in, const int* in_sizes, int n_in,
                              void* d_out, int out_size, void* d_ws, size_t ws_size,
                              hipStream_t stream) {
  const float* x    = (const float*)d_in[0];
  const float* Wk_f = (const float*)d_in[1];
  const float* Wr_f = (const float*)d_in[2];
  const float* b_f  = (const float*)d_in[3];
  const float* Wk_b = (const float*)d_in[4];
  const float* Wr_b = (const float*)d_in[5];
  const float* b_b  = (const float*)d_in[6];
  float* out = (float*)d_out;

  const size_t XPH = (size_t)2*T_STEPS*COLS4U*BATCH*sizeof(_Float16);   // 64 MiB
  const size_t SL  = (size_t)2*8*2048*sizeof(unsigned);                 // 128 KiB
  const size_t RT  = 256;                                               // regtab

  if (ws_size >= XPH + SL + RT) {
    _Float16* xph    = (_Float16*)d_ws;
    unsigned* slices = (unsigned*)((char*)d_ws + XPH);
    unsigned* regtab = (unsigned*)((char*)d_ws + XPH + SL);
    hipMemsetAsync(regtab, 0, RT, stream);          // fresh election each launch
    xproj<<<512, 256, 0, stream>>>(x, Wk_f, b_f, Wk_b, b_b, xph);
    bilstm_scan_xcd<<<NCAND, 256, 0, stream>>>(Wr_f, Wr_b, out, xph, slices, regtab);
  } else {
    unsigned short* slices = (unsigned short*)d_ws;
    unsigned* flags = (unsigned*)((char*)d_ws + 65536);
    hipMemsetAsync((char*)d_ws + 65536, 0, 1024, stream);
    bilstm_mfma<<<8, 256, 0, stream>>>(x, Wk_f, Wr_f, b_f, Wk_b, Wr_b, b_b,
                                       out, slices, flags);
  }
}